// Round 11
// baseline (336.713 us; speedup 1.0000x reference)
//
#include <hip/hip_runtime.h>
#include <hip/hip_bf16.h>
#include <hip/hip_fp16.h>

// GCNDecoder: 2-layer GCN, N=100000, E=1600000, 64 -> 128 -> 64, fp32.
//
// R1: agg-before-GEMM (linearity), dst-CSR + gather agg (no fp32 atomics).
// R2-R8 scatter lesson: workgroup->XCD placement is NOT controllable; any
//   random global 4B store/atomic costs ~32-64B HBM write. All random
//   placement happens in LDS; HBM access strictly coalesced.
// R3/R5/R9: f16 gather features pre-scaled by dinv[src]; 8-edge MLP unroll
//   + index prefetch. agg FETCH is pinned at ~87 MB = the 8-XCD gather
//   redundancy floor for a 12.8 MB f16 feature table (R10 confirmed:
//   latency tweaks moved dur 59->55 us, FETCH barely moved). agg is
//   structurally done.
// R10: gemm1+gemm2 FUSED: h = relu(xh W3 + b3) lives only in a f16 LDS tile
//   (identical numerics to the old f16 r round-trip), then t = (h W4)*dinv.
//   Kills 51 MB of HBM traffic (r write+read) and one launch. LDS 65 KB ->
//   2 blocks/CU. cvt vectorized to float4/uint2.
//
// Pipeline:
//   zero_small -> bhist(196 LDS hist) -> bscan -> bin(ebuf u32)
//   -> bucket(row_start+dinv+sorted_src, all LDS-staged)
//   -> cvt(x*dinv -> xh f16) -> agg(xh -> agg_x f16)
//   -> gemm_fused (t = (relu(agg_x W3 + b3) W4) * dinv, f16)
//   -> agg(t -> out f32, +b4)

constexpr int IN_C  = 64;
constexpr int HID_C = 128;
constexpr int OUT_C = 64;
constexpr int BSHIFT = 9;                 // bucket width = 512 dst nodes
constexpr int BW     = 1 << BSHIFT;
constexpr int TILE   = 4096;              // bin tile (16 edges/thread)
constexpr int FCAP   = 16384;             // bucket LDS region cap (64 KB)

__device__ __forceinline__ float2 up2(unsigned u) {      // unpack f16x2
    __half2 h = *reinterpret_cast<__half2*>(&u);
    return __half22float2(h);
}
__device__ __forceinline__ unsigned pk2(float a, float b) {  // pack f16x2
    __half2 h = __float22half2_rn(make_float2(a, b));
    return *reinterpret_cast<unsigned*>(&h);
}

__global__ __launch_bounds__(256) void zero_small_kernel(int* __restrict__ p, int m)
{
    int i = blockIdx.x * 256 + threadIdx.x;
    if (i < m) p[i] = 0;
}

// Per-block LDS histogram over buckets (d>>9); one nbkt-atomic flush/block.
__global__ __launch_bounds__(256) void bhist_kernel(
    const int* __restrict__ dst, int* __restrict__ bcnt, int E, int nbkt)
{
    __shared__ int h[256];
    h[threadIdx.x] = 0;
    __syncthreads();
    const int stride = gridDim.x * 256;
    for (int e = blockIdx.x * 256 + threadIdx.x; e < E; e += stride) {
        int d = __builtin_nontemporal_load(&dst[e]);
        atomicAdd(&h[d >> BSHIFT], 1);
    }
    __syncthreads();
    if (threadIdx.x < nbkt && h[threadIdx.x] != 0)
        atomicAdd(&bcnt[threadIdx.x], h[threadIdx.x]);
}

// Single-block exclusive scan of bcnt[nbkt] -> bbase[nbkt+1]; bcur=bbase.
__global__ __launch_bounds__(256) void bscan_kernel(
    const int* __restrict__ bcnt, int* __restrict__ bbase,
    int* __restrict__ bcur, int nbkt)
{
    __shared__ int s[256];
    int v = (threadIdx.x < nbkt) ? bcnt[threadIdx.x] : 0;
    s[threadIdx.x] = v;
    __syncthreads();
    for (int off = 1; off < 256; off <<= 1) {
        int t = (threadIdx.x >= off) ? s[threadIdx.x - off] : 0;
        __syncthreads();
        s[threadIdx.x] += t;
        __syncthreads();
    }
    if (threadIdx.x < nbkt) {
        int ex = s[threadIdx.x] - v;
        bbase[threadIdx.x] = ex;
        bcur[threadIdx.x]  = ex;
        if (threadIdx.x == nbkt - 1) bbase[nbkt] = s[threadIdx.x];
    }
}

// Bin edges into nbkt contiguous regions of ebuf, PACKED u32 per edge:
// w = (src << 9) | (dst & 511). Edges live in registers (16/thread);
// bucket-grouped via LDS; flush coalesced. Parallel 256-wide scan.
__global__ __launch_bounds__(256) void bin_kernel(
    const int* __restrict__ src, const int* __restrict__ dst,
    int* __restrict__ bcur, unsigned* __restrict__ ebuf, int E, int nbkt)
{
    __shared__ unsigned stageS[TILE];           // 16 KB bucket-grouped
    __shared__ unsigned char stageB[TILE];      // 4 KB bucket ids
    __shared__ int lcnt[256], lofs[256], lpos[256], gbase[256], s[256];
    const int base = blockIdx.x * TILE;
    const int cnt_mine = min(TILE, E - base);
    const int t = threadIdx.x;
    lcnt[t] = 0;
    __syncthreads();
    unsigned w[16]; int p[16];
    #pragma unroll
    for (int k = 0; k < 16; ++k) {
        int jo = t + k * 256;
        if (jo < cnt_mine) {
            int sv = __builtin_nontemporal_load(&src[base + jo]);
            int dv = __builtin_nontemporal_load(&dst[base + jo]);
            p[k] = dv >> BSHIFT;
            w[k] = ((unsigned)sv << BSHIFT) | (unsigned)(dv & (BW - 1));
            atomicAdd(&lcnt[p[k]], 1);
        } else p[k] = -1;
    }
    __syncthreads();
    int v = lcnt[t];                             // parallel exclusive scan
    s[t] = v;
    __syncthreads();
    for (int off = 1; off < 256; off <<= 1) {
        int u = (t >= off) ? s[t - off] : 0;
        __syncthreads();
        s[t] += u;
        __syncthreads();
    }
    lofs[t] = s[t] - v;
    lpos[t] = s[t] - v;
    if (t < nbkt && v != 0) gbase[t] = atomicAdd(&bcur[t], v);
    __syncthreads();
    #pragma unroll
    for (int k = 0; k < 16; ++k) {
        if (p[k] >= 0) {
            int pos = atomicAdd(&lpos[p[k]], 1);
            stageS[pos] = w[k];
            stageB[pos] = (unsigned char)p[k];
        }
    }
    __syncthreads();
    for (int j = t; j < cnt_mine; j += 256) {
        int b = stageB[j];
        ebuf[gbase[b] + (j - lofs[b])] = stageS[j];
    }
}

// One block per bucket: per-node LDS hist of the region, LDS scan (512),
// coalesced row_start+dinv emit, LDS-cursor placement, coalesced flush.
__global__ __launch_bounds__(256) void bucket_kernel(
    const unsigned* __restrict__ ebuf, const int* __restrict__ bbase,
    int* __restrict__ row_start, float* __restrict__ dinv,
    int* __restrict__ sorted_src, int n, int E, int nbkt)
{
    __shared__ int lcnt[BW];
    __shared__ int lcur[BW];
    __shared__ int s[256];
    __shared__ int lsrc[FCAP];                // 64 KB staging
    const int b   = blockIdx.x;
    const int lo  = b << BSHIFT;
    const int hi  = min(lo + BW, n);
    const int nn  = hi - lo;
    const int beg = bbase[b], end = bbase[b + 1];
    const int cnt = end - beg;
    const int t   = threadIdx.x;
    for (int i = t; i < nn; i += 256) lcnt[i] = 0;
    __syncthreads();
    for (int j = beg + t; j < end; j += 256)
        atomicAdd(&lcnt[ebuf[j] & (BW - 1)], 1);
    __syncthreads();
    int a0 = (2 * t     < nn) ? lcnt[2 * t]     : 0;
    int a1 = (2 * t + 1 < nn) ? lcnt[2 * t + 1] : 0;
    int tsum = a0 + a1;
    s[t] = tsum;
    __syncthreads();
    for (int off = 1; off < 256; off <<= 1) {
        int v = (t >= off) ? s[t - off] : 0;
        __syncthreads();
        s[t] += v;
        __syncthreads();
    }
    int texcl = s[t] - tsum;
    if (2 * t < nn) {
        lcur[2 * t] = texcl;
        row_start[lo + 2 * t] = beg + texcl;
        dinv[lo + 2 * t] = rsqrtf((float)a0 + 1.0f);
    }
    if (2 * t + 1 < nn) {
        lcur[2 * t + 1] = texcl + a0;
        row_start[lo + 2 * t + 1] = beg + texcl + a0;
        dinv[lo + 2 * t + 1] = rsqrtf((float)a1 + 1.0f);
    }
    if (t == 0 && b == nbkt - 1) row_start[n] = E;
    __syncthreads();
    if (cnt <= FCAP) {
        for (int j = beg + t; j < end; j += 256) {
            unsigned w = ebuf[j];
            int pos = atomicAdd(&lcur[w & (BW - 1)], 1);
            lsrc[pos] = (int)(w >> BSHIFT);
        }
        __syncthreads();
        for (int j = t; j < cnt; j += 256)
            sorted_src[beg + j] = lsrc[j];
    } else {                                  // safety net (never on this graph)
        for (int j = beg + t; j < end; j += 256) {
            unsigned w = ebuf[j];
            int pos = atomicAdd(&lcur[w & (BW - 1)], 1);
            sorted_src[beg + pos] = (int)(w >> BSHIFT);
        }
    }
}

// Pack 4 fp32 channels into 2 f16x2 words, PRE-SCALED by dinv[row].
// i indexes groups of 4 channels: row = i>>4.
__global__ __launch_bounds__(256) void cvt_scaled_kernel(
    const float4* __restrict__ in, const float* __restrict__ dinv,
    uint2* __restrict__ outw, int nq)
{
    int i = blockIdx.x * 256 + threadIdx.x;
    if (i < nq) {
        float4 v = in[i];
        float dv = dinv[i >> 4];
        outw[i] = make_uint2(pk2(v.x * dv, v.y * dv), pk2(v.z * dv, v.w * dv));
    }
}

// One wave per dst node. feat is packed f16, PRE-SCALED by dinv[src].
// Half-wave-per-edge, 4 edges per half in flight; next batch's indices
// prefetched while current gathers are outstanding.
// out[d] = dinv_d * (feat'[d] + sum_s feat'[s]) [+ bias].
template <bool OUT_F16, bool ADD_BIAS>
__global__ __launch_bounds__(256) void agg_f16_kernel(
    const unsigned* __restrict__ feat, const int* __restrict__ row_start,
    const int* __restrict__ sorted_src, const float* __restrict__ dinv,
    const float* __restrict__ bias, void* __restrict__ outp, int n)
{
    const int wv   = threadIdx.x >> 6;
    const int lane = threadIdx.x & 63;
    const int half = lane >> 5;
    const int lc   = lane & 31;
    const int d    = blockIdx.x * 4 + wv;
    if (d >= n) return;                 // wave-uniform exit
    const float di = dinv[d];
    float ax = 0.0f, ay = 0.0f;
    if (half == 0) {                    // self-loop term (feat already scaled)
        float2 f = up2(feat[(size_t)d * 32 + lc]);
        ax = f.x;
        ay = f.y;
    }
    const int beg = row_start[d], end = row_start[d + 1];
    int i = beg + half;
    int s0, s1, s2, s3;
    if (i + 6 < end) {
        s0 = sorted_src[i]; s1 = sorted_src[i + 2];
        s2 = sorted_src[i + 4]; s3 = sorted_src[i + 6];
    }
    while (i + 6 < end) {
        unsigned u0 = feat[(size_t)s0 * 32 + lc];
        unsigned u1 = feat[(size_t)s1 * 32 + lc];
        unsigned u2 = feat[(size_t)s2 * 32 + lc];
        unsigned u3 = feat[(size_t)s3 * 32 + lc];
        int ni = i + 8;
        if (ni + 6 < end) {             // prefetch next batch's indices
            s0 = sorted_src[ni]; s1 = sorted_src[ni + 2];
            s2 = sorted_src[ni + 4]; s3 = sorted_src[ni + 6];
        }
        float2 f0 = up2(u0), f1 = up2(u1), f2 = up2(u2), f3 = up2(u3);
        ax += f0.x; ay += f0.y;
        ax += f1.x; ay += f1.y;
        ax += f2.x; ay += f2.y;
        ax += f3.x; ay += f3.y;
        i = ni;
    }
    for (; i < end; i += 2) {           // remainder (each half strides 2)
        float2 f0 = up2(feat[(size_t)sorted_src[i] * 32 + lc]);
        ax += f0.x; ay += f0.y;
    }
    float ox = ax + __shfl(ax, lane + 32);
    float oy = ay + __shfl(ay, lane + 32);
    if (half == 0) {
        ox *= di; oy *= di;
        if (ADD_BIAS) {
            const float2 bv = ((const float2*)bias)[lc];
            ox += bv.x; oy += bv.y;
        }
        if (OUT_F16) ((unsigned*)outp)[(size_t)d * 32 + lc] = pk2(ox, oy);
        else         ((float2*)outp)[(size_t)d * 32 + lc] = make_float2(ox, oy);
    }
}

// FUSED: t[row][c] = dinv[row] * sum_k relu(xh[row] W3 + b3)[k] * W4[k][c].
// 64-row tile; h lives only in a f16 LDS tile (numerics identical to the
// old f16 r round-trip). Stage 1: 16x8 cols x 4 rows. Stage 2: 8x8 cols x
// 2 rows per thread. LDS ~65 KB -> 2 blocks/CU.
__global__ __launch_bounds__(256) void gemm_fused_kernel(
    const unsigned* __restrict__ xh, const float* __restrict__ W3,
    const float* __restrict__ b3, const float* __restrict__ W4,
    const float* __restrict__ dinv, unsigned* __restrict__ tout, int n)
{
    __shared__ unsigned Wh3[IN_C * 64];     // f16x2 [k][c/2], 16 KB (c<128)
    __shared__ unsigned Wh4[HID_C * 32];    // f16x2 [k][c/2], 16 KB (c<64)
    __shared__ float    xs[64][IN_C + 1];   // 16.6 KB
    __shared__ unsigned hs[64][65];         // f16x2 h tile, 16.6 KB (128 ch)
    const int t = threadIdx.x;
    for (int i = t; i < IN_C * 64; i += 256) {
        int k = i >> 6, cp = i & 63;
        Wh3[i] = pk2(W3[k * HID_C + cp * 2], W3[k * HID_C + cp * 2 + 1]);
    }
    for (int i = t; i < HID_C * 32; i += 256) {
        int k = i >> 5, cp = i & 31;
        Wh4[i] = pk2(W4[k * OUT_C + cp * 2], W4[k * OUT_C + cp * 2 + 1]);
    }
    const int r0 = blockIdx.x * 64;
    for (int i = t; i < 64 * 32; i += 256) {
        int row = i >> 5, c = i & 31;
        int r = r0 + row;
        float2 f = up2((r < n) ? xh[(size_t)r * 32 + c] : 0u);
        xs[row][c * 2]     = f.x;
        xs[row][c * 2 + 1] = f.y;
    }
    __syncthreads();
    {   // stage 1: h = relu(xs W3 + b3) -> hs (f16x2)
        const int ct = t & 15;    // 16 x 8 = 128 cols
        const int rt = t >> 4;    // 16 x 4 = 64 rows
        float acc[4][8] = {};
        for (int k = 0; k < IN_C; ++k) {
            uint4 wq = *(const uint4*)&Wh3[k * 64 + ct * 4];
            float2 wa = up2(wq.x), wb = up2(wq.y), wc = up2(wq.z), wd = up2(wq.w);
            #pragma unroll
            for (int ry = 0; ry < 4; ++ry) {
                float xv = xs[rt * 4 + ry][k];
                acc[ry][0] += xv * wa.x; acc[ry][1] += xv * wa.y;
                acc[ry][2] += xv * wb.x; acc[ry][3] += xv * wb.y;
                acc[ry][4] += xv * wc.x; acc[ry][5] += xv * wc.y;
                acc[ry][6] += xv * wd.x; acc[ry][7] += xv * wd.y;
            }
        }
        float4 b0 = ((const float4*)b3)[ct * 2];
        float4 b1 = ((const float4*)b3)[ct * 2 + 1];
        #pragma unroll
        for (int ry = 0; ry < 4; ++ry) {
            int row = rt * 4 + ry;
            hs[row][ct * 4]     = pk2(fmaxf(acc[ry][0] + b0.x, 0.0f),
                                      fmaxf(acc[ry][1] + b0.y, 0.0f));
            hs[row][ct * 4 + 1] = pk2(fmaxf(acc[ry][2] + b0.z, 0.0f),
                                      fmaxf(acc[ry][3] + b0.w, 0.0f));
            hs[row][ct * 4 + 2] = pk2(fmaxf(acc[ry][4] + b1.x, 0.0f),
                                      fmaxf(acc[ry][5] + b1.y, 0.0f));
            hs[row][ct * 4 + 3] = pk2(fmaxf(acc[ry][6] + b1.z, 0.0f),
                                      fmaxf(acc[ry][7] + b1.w, 0.0f));
        }
    }
    __syncthreads();
    {   // stage 2: t = (hs W4) * dinv
        const int ct = t & 7;     // 8 x 8 = 64 cols
        const int rt = t >> 3;    // 32 x 2 = 64 rows
        float acc[2][8] = {};
        for (int k2 = 0; k2 < 64; ++k2) {       // k2 = k/2 over HID_C
            uint4 wq0 = *(const uint4*)&Wh4[(2 * k2)     * 32 + ct * 4];
            uint4 wq1 = *(const uint4*)&Wh4[(2 * k2 + 1) * 32 + ct * 4];
            float2 wa0 = up2(wq0.x), wb0 = up2(wq0.y), wc0 = up2(wq0.z), wd0 = up2(wq0.w);
            float2 wa1 = up2(wq1.x), wb1 = up2(wq1.y), wc1 = up2(wq1.z), wd1 = up2(wq1.w);
            #pragma unroll
            for (int ry = 0; ry < 2; ++ry) {
                float2 hv = up2(hs[rt * 2 + ry][k2]);
                acc[ry][0] += hv.x * wa0.x + hv.y * wa1.x;
                acc[ry][1] += hv.x * wa0.y + hv.y * wa1.y;
                acc[ry][2] += hv.x * wb0.x + hv.y * wb1.x;
                acc[ry][3] += hv.x * wb0.y + hv.y * wb1.y;
                acc[ry][4] += hv.x * wc0.x + hv.y * wc1.x;
                acc[ry][5] += hv.x * wc0.y + hv.y * wc1.y;
                acc[ry][6] += hv.x * wd0.x + hv.y * wd1.x;
                acc[ry][7] += hv.x * wd0.y + hv.y * wd1.y;
            }
        }
        #pragma unroll
        for (int ry = 0; ry < 2; ++ry) {
            int r = r0 + rt * 2 + ry;
            if (r < n) {
                float dv = dinv[r];
                uint4 o;
                o.x = pk2(acc[ry][0] * dv, acc[ry][1] * dv);
                o.y = pk2(acc[ry][2] * dv, acc[ry][3] * dv);
                o.z = pk2(acc[ry][4] * dv, acc[ry][5] * dv);
                o.w = pk2(acc[ry][6] * dv, acc[ry][7] * dv);
                *(uint4*)&tout[(size_t)r * 32 + ct * 4] = o;
            }
        }
    }
}

extern "C" void kernel_launch(void* const* d_in, const int* in_sizes, int n_in,
                              void* d_out, int out_size, void* d_ws, size_t ws_size,
                              hipStream_t stream)
{
    const float* x  = (const float*)d_in[0];
    const int*   ei = (const int*)d_in[1];
    const float* W3 = (const float*)d_in[2];
    const float* b3 = (const float*)d_in[3];
    const float* W4 = (const float*)d_in[4];
    const float* b4 = (const float*)d_in[5];
    float* out = (float*)d_out;

    const int n = in_sizes[0] / IN_C;   // 100000
    const int E = in_sizes[1] / 2;      // 1600000
    const int* src = ei;
    const int* dst = ei + E;
    const int nbkt = (n + BW - 1) >> BSHIFT;   // 196

    const size_t n_pad = ((size_t)n + 256) & ~(size_t)255;  // room for row_start[n]

    // Workspace: bcnt(256) | bbase(512) | bcur(256) | row_start | dinv |
    //            ssrc | ebuf (E u32) | xh (n*32 u32, reused as t) |
    //            agg_x (n*32 u32)
    int*      bcnt      = (int*)d_ws;
    int*      bbase     = bcnt + 256;
    int*      bcur      = bbase + 512;
    int*      row_start = bcur + 256;
    float*    dinv      = (float*)(row_start + n_pad);
    int*      ssrc      = (int*)(dinv + n_pad);
    unsigned* ebuf      = (unsigned*)(ssrc + (((size_t)E + 255) & ~(size_t)255));
    unsigned* xh        = ebuf + (((size_t)E + 255) & ~(size_t)255);
    unsigned* agg_x     = xh + n_pad * 32;
    unsigned* t         = xh;                      // xh dead after agg1

    zero_small_kernel<<<1, 256, 0, stream>>>(bcnt, 256);
    bhist_kernel<<<256, 256, 0, stream>>>(dst, bcnt, E, nbkt);
    bscan_kernel<<<1, 256, 0, stream>>>(bcnt, bbase, bcur, nbkt);

    bin_kernel<<<(E + TILE - 1) / TILE, 256, 0, stream>>>(src, dst, bcur, ebuf, E, nbkt);
    bucket_kernel<<<nbkt, 256, 0, stream>>>(ebuf, bbase, row_start, dinv, ssrc, n, E, nbkt);

    cvt_scaled_kernel<<<(n * 16 + 255) / 256, 256, 0, stream>>>(
        (const float4*)x, dinv, (uint2*)xh, n * 16);

    agg_f16_kernel<true, false><<<(n + 3) / 4, 256, 0, stream>>>(
        xh, row_start, ssrc, dinv, nullptr, agg_x, n);

    gemm_fused_kernel<<<(n + 63) / 64, 256, 0, stream>>>(
        agg_x, W3, b3, W4, dinv, t, n);

    agg_f16_kernel<false, true><<<(n + 3) / 4, 256, 0, stream>>>(
        t, row_start, ssrc, dinv, b4, out, n);
}